// Round 6
// baseline (146983.948 us; speedup 1.0000x reference)
//
#include <hip/hip_runtime.h>
#include <hip/hip_bf16.h>
#include <math.h>
#include <stdio.h>

#define NWG 256
#define NT  512
#define T_  128
#define L_  8

struct P {
  const float *data,*r,*y_d,*wte_w,*wte_b,*wpe,*ln1_w,*ln1_b,*qkv_w,*qkv_b,
              *proj_w,*proj_b,*ln2_w,*ln2_b,*fc_w,*fc_b,*mproj_w,*mproj_b,
              *lnf_w,*lnf_b,*head_w,*head_b;
  float *out, *y, *u, *hT, *oT, *part;
  __hip_bfloat16 *Kc, *Vc;
  int *sync;
};

__device__ __forceinline__ float bf2f(unsigned short u) {
  return __uint_as_float(((unsigned)u) << 16);
}

__device__ __forceinline__ void gatom_add(float* p_, float v) {
  __hip_atomic_fetch_add(p_, v, __ATOMIC_RELAXED, __HIP_MEMORY_SCOPE_AGENT);
}

// Per-group 2-level barrier: 8 sub-counters (8 WGs) -> root(8) -> gen bump.
// Agent-scope acq_rel (cross-XCD verified r1-r4).
__device__ __forceinline__ void gbar(int* sb, int gw) {
  __syncthreads();
  if (threadIdx.x == 0) {
    unsigned* gen = (unsigned*)(sb + 160);
    unsigned g0 = __hip_atomic_load(gen, __ATOMIC_RELAXED, __HIP_MEMORY_SCOPE_AGENT);
    int rr = __hip_atomic_fetch_add(sb + (gw >> 3) * 16, 1, __ATOMIC_ACQ_REL, __HIP_MEMORY_SCOPE_AGENT);
    if (rr == 7) {
      __hip_atomic_store(sb + (gw >> 3) * 16, 0, __ATOMIC_RELAXED, __HIP_MEMORY_SCOPE_AGENT);
      int rt = __hip_atomic_fetch_add(sb + 128, 1, __ATOMIC_ACQ_REL, __HIP_MEMORY_SCOPE_AGENT);
      if (rt == 7) {
        __hip_atomic_store(sb + 128, 0, __ATOMIC_RELAXED, __HIP_MEMORY_SCOPE_AGENT);
        __hip_atomic_fetch_add(gen, 1u, __ATOMIC_RELEASE, __HIP_MEMORY_SCOPE_AGENT);
      }
    }
    while (__hip_atomic_load(gen, __ATOMIC_RELAXED, __HIP_MEMORY_SCOPE_AGENT) == g0)
      __builtin_amdgcn_s_sleep(2);
    (void)__hip_atomic_load(gen, __ATOMIC_ACQUIRE, __HIP_MEMORY_SCOPE_AGENT);
  }
  __syncthreads();
}

// Row stats (mean/rstd) over hT[512][16] -> mu_s/rs_s[16].
__device__ __forceinline__ void stats16(const float* __restrict__ act,
                                        float* red, float* red2,
                                        float* mu_s, float* rs_s) {
  const int tid = threadIdx.x;
  const int m = tid & 15, kb = tid >> 4;
  float s = 0.f, s2 = 0.f;
  #pragma unroll
  for (int j = 0; j < 16; ++j) {
    const float v = act[(kb + j * 32) * 16 + m];
    s += v; s2 += v * v;
  }
  red[tid] = s; red2[tid] = s2;
  __syncthreads();
  if (tid < 16) {
    float a = 0.f, b = 0.f;
    #pragma unroll 8
    for (int i = 0; i < 32; ++i) { a += red[i * 16 + tid]; b += red2[i * 16 + tid]; }
    const float mu = a * (1.f / 512.f);
    const float var = b * (1.f / 512.f) - mu * mu;
    mu_s[tid] = mu; rs_s[tid] = rsqrtf(var + 1e-5f);
  }
  __syncthreads();
}

#define FMA_ALL(W_, A_) \
  A_[0]+=W_*a0.x; A_[1]+=W_*a0.y; A_[2]+=W_*a0.z; A_[3]+=W_*a0.w; \
  A_[4]+=W_*a1.x; A_[5]+=W_*a1.y; A_[6]+=W_*a1.z; A_[7]+=W_*a1.w; \
  A_[8]+=W_*a2.x; A_[9]+=W_*a2.y; A_[10]+=W_*a2.z; A_[11]+=W_*a2.w; \
  A_[12]+=W_*a3.x; A_[13]+=W_*a3.y; A_[14]+=W_*a3.z; A_[15]+=W_*a3.w;

// Per-wave GEMM over this WG's k-slice (KS k-rows held in slab[KS][16]).
// Wave owns 16 cols; lane = (kq=lane>>3)*8 + (cp=lane&7): cols col0+cp*2,
// k subset {kq, kq+8, ...}. W loads: 8x64B segments = 512B/instr, coalesced.
// After 3 shfl_xor rounds (8/16/32) ALL lanes hold the full k-slice sum for
// their (cp) column pair; kq==0 lanes are designated writers.
template<int KS>
__device__ __forceinline__ void gemm_wave(const float* __restrict__ Wg, int N,
                                          const float* __restrict__ slab, int kq,
                                          float* acc0, float* acc1) {
  constexpr int NI = KS / 8;
  constexpr int BAT = NI < 8 ? NI : 8;
  #pragma unroll
  for (int jb = 0; jb < NI; jb += BAT) {
    float2 w[BAT];
    #pragma unroll
    for (int u = 0; u < BAT; ++u)
      w[u] = *(const float2*)(Wg + (size_t)((jb + u) * 8) * N);
    #pragma unroll
    for (int u = 0; u < BAT; ++u) {
      const float* ar = slab + (kq + (jb + u) * 8) * 16;
      const float4 a0 = *(const float4*)ar,       a1 = *(const float4*)(ar + 4),
                   a2 = *(const float4*)(ar + 8), a3 = *(const float4*)(ar + 12);
      const float wx = w[u].x, wy = w[u].y;
      FMA_ALL(wx, acc0)
      FMA_ALL(wy, acc1)
    }
  }
  #pragma unroll
  for (int m = 0; m < 16; ++m) {
    acc0[m] += __shfl_xor(acc0[m], 8);
    acc1[m] += __shfl_xor(acc1[m], 8);
    acc0[m] += __shfl_xor(acc0[m], 16);
    acc1[m] += __shfl_xor(acc1[m], 16);
    acc0[m] += __shfl_xor(acc0[m], 32);
    acc1[m] += __shfl_xor(acc1[m], 32);
  }
}

__global__ __launch_bounds__(NT, 1) void gptloop(P p) {
  const int bid = blockIdx.x, tid = threadIdx.x;
  const int g  = (bid & 7) >> 1;              // XCD-pair group 0..3, 16 rows each
  const int gw = (bid >> 3) * 2 + (bid & 1);  // 0..63 within group
  int* sb = p.sync + g * 256;
  float* hTg   = p.hT + g * 8192;             // [512][16]
  float* oTg   = p.oT + g * 8192;             // [512][16]
  float* partg = p.part + (size_t)g * 131072; // [4][N<=2048][16]

  __shared__ float a_slab[2048];
  __shared__ float red1[512], red2[512];
  __shared__ float att_s[2][128];
  __shared__ float qv_s[2][64];
  __shared__ float inv_s[2];
  __shared__ float mu_s[16], rs_s[16], bc[4];

  const int wv = tid >> 6, lane = tid & 63;
  const int kq = lane >> 3, cp = lane & 7;

  // ---- init: y/u state + embed(st=0), 16 WGs x 1 row ----
  if (gw < 16) {
    const int m = gw, b = g * 16 + m;
    const float y0 = p.y_d[b * 256], y1 = p.y_d[b * 256 + 1];
    const float e0 = p.r[b * 256] - y0, e1 = p.r[b * 256 + 1] - y1;
    const float v = e0 * p.wte_w[tid] + e1 * p.wte_w[512 + tid]
                  + 191.713f * p.wte_w[1024 + tid] + 215.888f * p.wte_w[1536 + tid]
                  + p.wte_b[tid] + p.wpe[tid];
    hTg[tid * 16 + m] = v;
    if (tid < 2) {
      p.y[b * 2 + tid] = tid ? y1 : y0;
      p.u[b * 2 + tid] = tid ? 215.888f : 191.713f;
    }
  }
  gbar(sb, gw);

  for (int st = 0; st < T_; ++st) {
    for (int l = 0; l < L_; ++l) {
      // ---- qkv (+LN1): 48 WGs = 12 colblocks x 4 kslices -> partials ----
      if (gw < 48) {
        const int cb = gw >> 2, ks = gw & 3;
        stats16(hTg, red1, red2, mu_s, rs_s);
        const float* lnw = p.ln1_w + l * 512;
        const float* lnb = p.ln1_b + l * 512;
        #pragma unroll
        for (int j = 0; j < 4; ++j) {
          const int e = tid + j * 512, kl = e >> 4, rr2 = e & 15, kg = ks * 128 + kl;
          a_slab[e] = (hTg[kg * 16 + rr2] - mu_s[rr2]) * rs_s[rr2] * lnw[kg] + lnb[kg];
        }
        __syncthreads();
        const int col = cb * 128 + wv * 16 + cp * 2;
        float acc0[16], acc1[16];
        #pragma unroll
        for (int m = 0; m < 16; ++m) { acc0[m] = 0.f; acc1[m] = 0.f; }
        gemm_wave<128>(p.qkv_w + (size_t)l * 786432 + (size_t)(ks * 128 + kq) * 1536 + col,
                       1536, a_slab, kq, acc0, acc1);
        if (kq == 0) {
          float* op = partg + ((size_t)ks * 1536 + col) * 16;
          #pragma unroll
          for (int q4 = 0; q4 < 4; ++q4) {
            *(float4*)(op + q4 * 4)      = make_float4(acc0[q4*4], acc0[q4*4+1], acc0[q4*4+2], acc0[q4*4+3]);
            *(float4*)(op + 16 + q4 * 4) = make_float4(acc1[q4*4], acc1[q4*4+1], acc1[q4*4+2], acc1[q4*4+3]);
          }
        }
      }
      gbar(sb, gw);

      // ---- attention: 64 WGs x 2 (b,h) pairs; 4-way qkv partial reduce ----
      {
        const int pp = tid >> 8, t = tid & 255;
        const int pid = gw * 2 + pp, bl = pid >> 3, hh = pid & 7;
        const int b = g * 16 + bl;
        const size_t kvb = ((size_t)(l * 64 + b) * 8 + hh) * (size_t)8192;
        if (t < 64) {
          const int qcol = hh * 64 + t, kcol = qcol + 512, vcol = qcol + 1024;
          const float qs = partg[(size_t)qcol*16+bl] + partg[(1536+(size_t)qcol)*16+bl]
                         + partg[(3072+(size_t)qcol)*16+bl] + partg[(4608+(size_t)qcol)*16+bl]
                         + p.qkv_b[l * 1536 + qcol];
          qv_s[pp][t] = qs * 0.125f;
          const float kv = partg[(size_t)kcol*16+bl] + partg[(1536+(size_t)kcol)*16+bl]
                         + partg[(3072+(size_t)kcol)*16+bl] + partg[(4608+(size_t)kcol)*16+bl]
                         + p.qkv_b[l * 1536 + kcol];
          p.Kc[kvb + st * 64 + t] = __float2bfloat16(kv);
          const float vv = partg[(size_t)vcol*16+bl] + partg[(1536+(size_t)vcol)*16+bl]
                         + partg[(3072+(size_t)vcol)*16+bl] + partg[(4608+(size_t)vcol)*16+bl]
                         + p.qkv_b[l * 1536 + vcol];
          p.Vc[kvb + st * 64 + t] = __float2bfloat16(vv);
        }
        __syncthreads();
        float s = -1e30f;
        if (t <= st && t < 128) {
          const uint4* kp = (const uint4*)((const unsigned short*)p.Kc + kvb + (size_t)t * 64);
          float sc = 0.f;
          #pragma unroll
          for (int j2 = 0; j2 < 8; ++j2) {
            const uint4 k4 = kp[j2];
            sc += qv_s[pp][j2*8+0] * bf2f((unsigned short)k4.x)
                + qv_s[pp][j2*8+1] * bf2f((unsigned short)(k4.x >> 16))
                + qv_s[pp][j2*8+2] * bf2f((unsigned short)k4.y)
                + qv_s[pp][j2*8+3] * bf2f((unsigned short)(k4.y >> 16))
                + qv_s[pp][j2*8+4] * bf2f((unsigned short)k4.z)
                + qv_s[pp][j2*8+5] * bf2f((unsigned short)(k4.z >> 16))
                + qv_s[pp][j2*8+6] * bf2f((unsigned short)k4.w)
                + qv_s[pp][j2*8+7] * bf2f((unsigned short)(k4.w >> 16));
          }
          s = sc;
        }
        red1[tid] = s; __syncthreads();
        for (int s2 = 128; s2 >= 1; s2 >>= 1) {
          if (t < s2) red1[tid] = fmaxf(red1[tid], red1[tid + s2]);
          __syncthreads();
        }
        const float mx = red1[pp * 256];
        __syncthreads();
        const float e = (t <= st && t < 128) ? expf(s - mx) : 0.f;
        if (t < 128) att_s[pp][t] = e;
        red1[tid] = e; __syncthreads();
        for (int s2 = 128; s2 >= 1; s2 >>= 1) {
          if (t < s2) red1[tid] += red1[tid + s2];
          __syncthreads();
        }
        if (t == 0) inv_s[pp] = 1.f / red1[pp * 256];
        __syncthreads();
        const int d = t & 63, tq = t >> 6;
        float o = 0.f;
        const unsigned short* vp = (const unsigned short*)p.Vc;
        for (int tt = tq; tt <= st; tt += 4)
          o += att_s[pp][tt] * bf2f(vp[kvb + (size_t)tt * 64 + d]);
        red1[tid] = o; __syncthreads();
        if (tid < 128) {
          const int p2 = tid >> 6, d2 = tid & 63;
          const int pid2 = gw * 2 + p2, bl2 = pid2 >> 3, h2 = pid2 & 7;
          const float oo = (red1[p2*256 + d2] + red1[p2*256 + 64 + d2]
                          + red1[p2*256 + 128 + d2] + red1[p2*256 + 192 + d2]) * inv_s[p2];
          oTg[(h2 * 64 + d2) * 16 + bl2] = oo;
        }
      }
      gbar(sb, gw);

      // ---- proj: 64 WGs = 4 colblocks x 16 kslices(32k) -> atomics into hTg ----
      {
        const int cb = gw >> 4, ks = gw & 15;
        if (tid < 512) a_slab[tid] = oTg[ks * 512 + tid];
        __syncthreads();
        const int col = cb * 128 + wv * 16 + cp * 2;
        float acc0[16], acc1[16];
        #pragma unroll
        for (int m = 0; m < 16; ++m) { acc0[m] = 0.f; acc1[m] = 0.f; }
        gemm_wave<32>(p.proj_w + (size_t)l * 262144 + (size_t)(ks * 32 + kq) * 512 + col,
                      512, a_slab, kq, acc0, acc1);
        if (kq == 0) {
          const float bs0 = (ks == 0) ? p.proj_b[l * 512 + col]     : 0.f;
          const float bs1 = (ks == 0) ? p.proj_b[l * 512 + col + 1] : 0.f;
          #pragma unroll
          for (int rr2 = 0; rr2 < 16; ++rr2) {
            gatom_add(&hTg[col * 16 + rr2],       acc0[rr2] + bs0);
            gatom_add(&hTg[(col + 1) * 16 + rr2], acc1[rr2] + bs1);
          }
        }
      }
      gbar(sb, gw);

      // ---- fc (+LN2): 64 WGs = 16 colblocks x 4 kslices -> partials ----
      {
        const int cb = gw >> 2, ks = gw & 3;
        stats16(hTg, red1, red2, mu_s, rs_s);
        const float* lnw = p.ln2_w + l * 512;
        const float* lnb = p.ln2_b + l * 512;
        #pragma unroll
        for (int j = 0; j < 4; ++j) {
          const int e = tid + j * 512, kl = e >> 4, rr2 = e & 15, kg = ks * 128 + kl;
          a_slab[e] = (hTg[kg * 16 + rr2] - mu_s[rr2]) * rs_s[rr2] * lnw[kg] + lnb[kg];
        }
        __syncthreads();
        const int col = cb * 128 + wv * 16 + cp * 2;
        float acc0[16], acc1[16];
        #pragma unroll
        for (int m = 0; m < 16; ++m) { acc0[m] = 0.f; acc1[m] = 0.f; }
        gemm_wave<128>(p.fc_w + (size_t)l * 1048576 + (size_t)(ks * 128 + kq) * 2048 + col,
                       2048, a_slab, kq, acc0, acc1);
        if (kq == 0) {
          float* op = partg + ((size_t)ks * 2048 + col) * 16;
          #pragma unroll
          for (int q4 = 0; q4 < 4; ++q4) {
            *(float4*)(op + q4 * 4)      = make_float4(acc0[q4*4], acc0[q4*4+1], acc0[q4*4+2], acc0[q4*4+3]);
            *(float4*)(op + 16 + q4 * 4) = make_float4(acc1[q4*4], acc1[q4*4+1], acc1[q4*4+2], acc1[q4*4+3]);
          }
        }
      }
      gbar(sb, gw);

      // ---- mproj: 64 WGs = 4 colblocks x 16 kslices(128k of 2048);
      //      stage = gelu(4-way fc-partial reduce + bias); atomics into hTg ----
      {
        const int cb = gw >> 4, ks = gw & 15;
        #pragma unroll
        for (int j = 0; j < 4; ++j) {
          const int e = tid + j * 512, kl = e >> 4, rr2 = e & 15, kg = ks * 128 + kl;
          const float x = partg[(size_t)kg*16+rr2] + partg[(2048+(size_t)kg)*16+rr2]
                        + partg[(4096+(size_t)kg)*16+rr2] + partg[(6144+(size_t)kg)*16+rr2]
                        + p.fc_b[l * 2048 + kg];
          a_slab[e] = 0.5f * x * (1.f + erff(x * 0.70710678118654752f));
        }
        __syncthreads();
        const int col = cb * 128 + wv * 16 + cp * 2;
        float acc0[16], acc1[16];
        #pragma unroll
        for (int m = 0; m < 16; ++m) { acc0[m] = 0.f; acc1[m] = 0.f; }
        gemm_wave<128>(p.mproj_w + (size_t)l * 1048576 + (size_t)(ks * 128 + kq) * 512 + col,
                       512, a_slab, kq, acc0, acc1);
        if (kq == 0) {
          const float bs0 = (ks == 0) ? p.mproj_b[l * 512 + col]     : 0.f;
          const float bs1 = (ks == 0) ? p.mproj_b[l * 512 + col + 1] : 0.f;
          #pragma unroll
          for (int rr2 = 0; rr2 < 16; ++rr2) {
            gatom_add(&hTg[col * 16 + rr2],       acc0[rr2] + bs0);
            gatom_add(&hTg[(col + 1) * 16 + rr2], acc1[rr2] + bs1);
          }
        }
      }
      gbar(sb, gw);
    } // layers

    // ---- final: lnf + head + ODE + out + embed(st+1): 16 WGs x 1 row ----
    if (gw < 16) {
      const int m = gw, b = g * 16 + m;
      const float v = hTg[tid * 16 + m];
      red1[tid] = v; red2[tid] = v * v;
      __syncthreads();
      for (int s2 = 256; s2 >= 1; s2 >>= 1) {
        if (tid < s2) { red1[tid] += red1[tid + s2]; red2[tid] += red2[tid + s2]; }
        __syncthreads();
      }
      const float mu = red1[0] * (1.f / 512.f);
      const float var = red2[0] * (1.f / 512.f) - mu * mu;
      const float rs = rsqrtf(var + 1e-5f);
      __syncthreads();
      const float hf = (v - mu) * rs * p.lnf_w[tid] + p.lnf_b[tid];
      red1[tid] = hf * p.head_w[tid * 2];
      red2[tid] = hf * p.head_w[tid * 2 + 1];
      __syncthreads();
      for (int s2 = 256; s2 >= 1; s2 >>= 1) {
        if (tid < s2) { red1[tid] += red1[tid + s2]; red2[tid] += red2[tid + s2]; }
        __syncthreads();
      }
      if (tid < 2) {
        const float un = ((tid == 0) ? red1[0] : red2[0]) + p.head_b[tid];
        const float a  = p.data[b * 4 + tid];
        const float bb = p.data[b * 4 + 2 + tid];
        const float yv = p.y[b * 2 + tid];
        p.out[b * 256 + st * 2 + tid] = yv;
        const float yn = yv - a * yv + bb * un;
        p.y[b * 2 + tid] = yn;
        p.u[b * 2 + tid] = un;
        bc[tid] = yn; bc[2 + tid] = un;
      }
      __syncthreads();
      if (st < T_ - 1) {
        const float e0 = p.r[b * 256 + (st + 1) * 2]     - bc[0];
        const float e1 = p.r[b * 256 + (st + 1) * 2 + 1] - bc[1];
        const float v2 = e0 * p.wte_w[tid] + e1 * p.wte_w[512 + tid]
                       + bc[2] * p.wte_w[1024 + tid] + bc[3] * p.wte_w[1536 + tid]
                       + p.wte_b[tid] + p.wpe[(st + 1) * 512 + tid];
        hTg[tid * 16 + m] = v2;
      }
    }
    gbar(sb, gw);
  } // steps
}

extern "C" void kernel_launch(void* const* d_in, const int* in_sizes, int n_in,
                              void* d_out, int out_size, void* d_ws, size_t ws_size,
                              hipStream_t stream) {
  P p;
  p.data  =(const float*)d_in[0];  p.r      =(const float*)d_in[1];
  p.y_d   =(const float*)d_in[2];  p.wte_w  =(const float*)d_in[3];
  p.wte_b =(const float*)d_in[4];  p.wpe    =(const float*)d_in[5];
  p.ln1_w =(const float*)d_in[6];  p.ln1_b  =(const float*)d_in[7];
  p.qkv_w =(const float*)d_in[8];  p.qkv_b  =(const float*)d_in[9];
  p.proj_w=(const float*)d_in[10]; p.proj_b =(const float*)d_in[11];
  p.ln2_w =(const float*)d_in[12]; p.ln2_b  =(const float*)d_in[13];
  p.fc_w  =(const float*)d_in[14]; p.fc_b   =(const float*)d_in[15];
  p.mproj_w=(const float*)d_in[16];p.mproj_b=(const float*)d_in[17];
  p.lnf_w =(const float*)d_in[18]; p.lnf_b  =(const float*)d_in[19];
  p.head_w=(const float*)d_in[20]; p.head_b =(const float*)d_in[21];
  p.out = (float*)d_out;

  char* w = (char*)d_ws;
  size_t off = 0;
  p.sync=(int*)(w+off);            off += 4096;
  p.y   =(float*)(w+off);          off += 512;
  p.u   =(float*)(w+off);          off += 512;
  p.hT  =(float*)(w+off);          off += (size_t)4*8192*4;
  p.oT  =(float*)(w+off);          off += (size_t)4*8192*4;
  p.part=(float*)(w+off);          off += (size_t)4*131072*4;
  p.Kc  =(__hip_bfloat16*)(w+off); off += (size_t)L_*64*8*T_*64*2;
  p.Vc  =(__hip_bfloat16*)(w+off); off += (size_t)L_*64*8*T_*64*2;

  fprintf(stderr, "[gptloop] ws_size=%zu need=%zu\n", ws_size, off);
  if (ws_size < off) return;

  hipMemsetAsync(d_ws, 0, 4096, stream);
  hipLaunchKernelGGL(gptloop, dim3(NWG), dim3(NT), 0, stream, p);
}